// Round 5
// baseline (1061.432 us; speedup 1.0000x reference)
//
#include <hip/hip_runtime.h>

#define Tn      8192
#define Cn      1024
#define En      8
#define Fn      2752
#define MAXROWS 17408
#define BM 128
#define NT1 43   // Fn/64 n-tiles in gemm1

typedef __bf16 bf16;
typedef bf16  bf16x8 __attribute__((ext_vector_type(8)));
typedef bf16  bf16x4 __attribute__((ext_vector_type(4)));
typedef float f32x4  __attribute__((ext_vector_type(4)));

__device__ __forceinline__ void gload16(const bf16* g, bf16* l) {
  __builtin_amdgcn_global_load_lds(
      (const __attribute__((address_space(1))) unsigned int*)g,
      (__attribute__((address_space(3))) unsigned int*)l, 16, 0, 0);
}

// ---------------- gating ------------------------------------------------------
__global__ __launch_bounds__(256) void gate_kernel(
    const float* __restrict__ x, const float* __restrict__ wgate,
    int* __restrict__ topk_i, float* __restrict__ topk_w, int* __restrict__ counts)
{
  int lane = threadIdx.x & 63;
  int wid  = threadIdx.x >> 6;
  int t = blockIdx.x * 4 + wid;
  const float4* xr4 = (const float4*)(x + (size_t)t * Cn);
  float acc[En];
#pragma unroll
  for (int e = 0; e < En; ++e) acc[e] = 0.f;
#pragma unroll
  for (int p = 0; p < Cn / 4 / 64; ++p) {
    int c4 = p * 64 + lane;
    float4 xv = xr4[c4];
#pragma unroll
    for (int e = 0; e < En; ++e) {
      float4 wv = *(const float4*)(wgate + (size_t)e * Cn + c4 * 4);
      acc[e] = fmaf(xv.x, wv.x, fmaf(xv.y, wv.y, fmaf(xv.z, wv.z, fmaf(xv.w, wv.w, acc[e]))));
    }
  }
#pragma unroll
  for (int e = 0; e < En; ++e) {
#pragma unroll
    for (int o = 32; o > 0; o >>= 1) acc[e] += __shfl_xor(acc[e], o, 64);
  }
  if (lane == 0) {
    float mx = acc[0];
#pragma unroll
    for (int e = 1; e < En; ++e) mx = fmaxf(mx, acc[e]);
    float p[En], Z = 0.f;
#pragma unroll
    for (int e = 0; e < En; ++e) { p[e] = __expf(acc[e] - mx); Z += p[e]; }
    int i0 = 0;
#pragma unroll
    for (int e = 1; e < En; ++e) if (p[e] > p[i0]) i0 = e;
    int i1 = (i0 == 0) ? 1 : 0;
#pragma unroll
    for (int e = 0; e < En; ++e) if (e != i0 && p[e] > p[i1]) i1 = e;
    float s0 = p[i0] / Z, s1 = p[i1] / Z;
    float inv = 1.f / (s0 + s1 + 1e-9f);
    topk_i[2 * t] = i0;       topk_i[2 * t + 1] = i1;
    topk_w[2 * t] = s0 * inv; topk_w[2 * t + 1] = s1 * inv;
    atomicAdd(&counts[i0], 1);
    atomicAdd(&counts[i1], 1);
  }
}

__global__ void offsets_kernel(const int* __restrict__ counts,
                               int* __restrict__ fill, int* __restrict__ off)
{
  if (threadIdx.x == 0 && blockIdx.x == 0) {
    int o = 0;
    for (int e = 0; e < En; ++e) {
      off[e]  = o;
      fill[e] = o;
      o += (counts[e] + BM - 1) & ~(BM - 1);
    }
    off[En] = o;
  }
}

__global__ __launch_bounds__(256) void scatter_kernel(
    const int* __restrict__ topk_i, const float* __restrict__ topk_w,
    int* __restrict__ fill, int* __restrict__ tok_list, float* __restrict__ wgt_list,
    int* __restrict__ inv_rows)
{
  int t = blockIdx.x * 256 + threadIdx.x;
#pragma unroll
  for (int j = 0; j < 2; ++j) {
    int e = topk_i[2 * t + j];
    int pos = atomicAdd(&fill[e], 1);
    tok_list[pos] = t;
    wgt_list[pos] = topk_w[2 * t + j];
    inv_rows[2 * t + j] = pos;
  }
}

__global__ __launch_bounds__(256) void gather_x(
    const float* __restrict__ x, const int* __restrict__ tok_list, bf16* __restrict__ xg)
{
  int row = blockIdx.x;
  int tok = tok_list[row];
  int c = threadIdx.x * 4;
  float4 v = make_float4(0.f, 0.f, 0.f, 0.f);
  if (tok >= 0) v = *(const float4*)(x + (size_t)tok * Cn + c);
  bf16x4 pv;
  pv[0] = (bf16)v.x; pv[1] = (bf16)v.y; pv[2] = (bf16)v.z; pv[3] = (bf16)v.w;
  *(bf16x4*)(xg + (size_t)row * Cn + c) = pv;
}

// ---------------- fast transpose + fp32->bf16 ---------------------------------
__global__ __launch_bounds__(256) void transpose_cvt(
    const float* __restrict__ src, bf16* __restrict__ dst, int M, int N)
{
  __shared__ float L[64][65];
  src += (size_t)blockIdx.z * M * N;
  dst += (size_t)blockIdx.z * M * N;
  const int bm = blockIdx.x * 64;
  const int bn = blockIdx.y * 64;
  const int tid = threadIdx.x;
  const int mr = tid >> 4, nseg = tid & 15;
#pragma unroll
  for (int p = 0; p < 4; ++p) {
    int m = p * 16 + mr;
    float4 v = *(const float4*)(src + (size_t)(bm + m) * N + bn + nseg * 4);
    L[nseg * 4 + 0][m] = v.x;
    L[nseg * 4 + 1][m] = v.y;
    L[nseg * 4 + 2][m] = v.z;
    L[nseg * 4 + 3][m] = v.w;
  }
  __syncthreads();
  const int nr = tid >> 3, mseg = tid & 7;
#pragma unroll
  for (int q = 0; q < 2; ++q) {
    int n = q * 32 + nr;
    bf16x8 w;
#pragma unroll
    for (int j = 0; j < 8; ++j) w[j] = (bf16)L[n][mseg * 8 + j];
    *(bf16x8*)(dst + (size_t)(bn + n) * M + bm + mseg * 8) = w;
  }
}

// LDS tile layout (BK=32, 64B rows = 4 x 16B slots):
//   LDS[row][slot] = G[row][slot ^ ((row>>1)&3)]   -> conflict-free b128 frag reads
// staging lane: row = lane>>2, gseg = (lane&3) ^ ((lane>>3)&3)
// frag read:   slot = q ^ ((fr>>1)&3),  q = lane>>4, fr = lane&15

// ---------------- GEMM1: h = wgt * silu(xg@wgT') * (xg@wuT') ------------------
// 128 x 64 (dual gate+up), BK=32.
// XCD-swizzled 1-D grid: xcd = b&7 owns n-stripe {xcd, xcd+8, ...}; within a
// stripe it sweeps all m consecutively -> 256KB weight n-slice stays L2-resident.
__global__ __launch_bounds__(256) void gemm1_kernel(
    const bf16* __restrict__ xg, const bf16* __restrict__ wgT, const bf16* __restrict__ wuT,
    const int* __restrict__ off, const int* __restrict__ counts,
    const float* __restrict__ wgt_list, bf16* __restrict__ h, int row_lo, int mt)
{
  const int b = blockIdx.x;
  const int k8 = b & 7, j = b >> 3;
  const int m_t = j % mt;
  const int n_t = k8 + 8 * (j / mt);
  if (n_t >= NT1) return;
  const int m0 = row_lo + m_t * BM;
  if (m0 >= off[En]) return;
  int e = 0;
  while (off[e + 1] <= m0) ++e;
  const int base = off[e], cnt = counts[e];
  const int n0 = n_t * 64;

  __shared__ bf16 As[128 * 32];
  __shared__ bf16 Bg[64 * 32];
  __shared__ bf16 Bu[64 * 32];

  const int tid = threadIdx.x;
  const int lane = tid & 63, wid = tid >> 6;
  const int wm = (wid >> 1) * 64, wn = (wid & 1) * 32;
  const int fr = lane & 15, q = lane >> 4;
  const int gseg = (lane & 3) ^ ((lane >> 3) & 3);
  const int lrow = lane >> 2;

  f32x4 z4; z4[0] = 0.f; z4[1] = 0.f; z4[2] = 0.f; z4[3] = 0.f;
  f32x4 accg[4][2], accu[4][2];
#pragma unroll
  for (int i = 0; i < 4; ++i)
#pragma unroll
    for (int jj = 0; jj < 2; ++jj) { accg[i][jj] = z4; accu[i][jj] = z4; }

  const bf16* wge = wgT + (size_t)e * Fn * Cn;
  const bf16* wue = wuT + (size_t)e * Fn * Cn;

  const bf16* agp = xg  + (size_t)(m0 + wid * 32 + lrow) * Cn + gseg * 8;
  const bf16* bgp = wge + (size_t)(n0 + wid * 16 + lrow) * Cn + gseg * 8;
  const bf16* bup = wue + (size_t)(n0 + wid * 16 + lrow) * Cn + gseg * 8;
  bf16* alp = As + wid * 32 * 32 + lane * 8;
  bf16* blg = Bg + wid * 16 * 32 + lane * 8;
  bf16* blu = Bu + wid * 16 * 32 + lane * 8;

  const int tt = (q ^ ((fr >> 1) & 3)) * 8;

  for (int kt = 0; kt < Cn / 32; ++kt) {
    __syncthreads();
    gload16(agp, alp);
    gload16(agp + (size_t)16 * Cn, alp + 16 * 32);
    gload16(bgp, blg);
    gload16(bup, blu);
    agp += 32; bgp += 32; bup += 32;
    __syncthreads();

    bf16x8 a[4], bg[2], bu[2];
#pragma unroll
    for (int mi = 0; mi < 4; ++mi)
      a[mi] = *(const bf16x8*)(As + (wm + mi * 16 + fr) * 32 + tt);
#pragma unroll
    for (int ni = 0; ni < 2; ++ni) {
      bg[ni] = *(const bf16x8*)(Bg + (wn + ni * 16 + fr) * 32 + tt);
      bu[ni] = *(const bf16x8*)(Bu + (wn + ni * 16 + fr) * 32 + tt);
    }
#pragma unroll
    for (int mi = 0; mi < 4; ++mi)
#pragma unroll
      for (int ni = 0; ni < 2; ++ni) {
        accg[mi][ni] = __builtin_amdgcn_mfma_f32_16x16x32_bf16(a[mi], bg[ni], accg[mi][ni], 0, 0, 0);
        accu[mi][ni] = __builtin_amdgcn_mfma_f32_16x16x32_bf16(a[mi], bu[ni], accu[mi][ni], 0, 0, 0);
      }
  }

  const int rq = (lane >> 4) * 4, cl = lane & 15;
#pragma unroll
  for (int mi = 0; mi < 4; ++mi) {
#pragma unroll
    for (int r = 0; r < 4; ++r) {
      int grow = m0 + wm + mi * 16 + rq + r;
      float w = (grow - base < cnt) ? wgt_list[grow] : 0.f;
      bf16* hr = h + (size_t)(grow - row_lo) * Fn + n0;
#pragma unroll
      for (int ni = 0; ni < 2; ++ni) {
        float g = accg[mi][ni][r], u = accu[mi][ni][r];
        float hv = w * u * (g / (1.f + __expf(-g)));
        hr[wn + ni * 16 + cl] = (bf16)hv;
      }
    }
  }
}

// ---------------- GEMM2: h2[row] = h[row] @ wdT'  (no atomics) ----------------
// 128 x 128, BK=32. XCD-swizzled: xcd = b&7 = n-tile (8 tiles), m = b>>3 sweeps;
// 704KB wd expert-slice L2-resident per XCD; all XCDs sweep m in lockstep.
__global__ __launch_bounds__(256) void gemm2_kernel(
    const bf16* __restrict__ h, const bf16* __restrict__ wdT,
    const int* __restrict__ off, bf16* __restrict__ h2, int row_lo)
{
  const int b = blockIdx.x;
  const int n_t = b & 7, m_t = b >> 3;
  const int m0 = row_lo + m_t * BM;
  if (m0 >= off[En]) return;
  int e = 0;
  while (off[e + 1] <= m0) ++e;
  const int n0 = n_t * 128;

  __shared__ bf16 As[128 * 32];
  __shared__ bf16 Bs[128 * 32];

  const int tid = threadIdx.x;
  const int lane = tid & 63, wid = tid >> 6;
  const int wm = (wid >> 1) * 64, wn = (wid & 1) * 64;
  const int fr = lane & 15, q = lane >> 4;
  const int gseg = (lane & 3) ^ ((lane >> 3) & 3);
  const int lrow = lane >> 2;

  f32x4 z4; z4[0] = 0.f; z4[1] = 0.f; z4[2] = 0.f; z4[3] = 0.f;
  f32x4 acc[4][4];
#pragma unroll
  for (int i = 0; i < 4; ++i)
#pragma unroll
    for (int jj = 0; jj < 4; ++jj) acc[i][jj] = z4;

  const bf16* wde = wdT + (size_t)e * Cn * Fn;
  const bf16* hb  = h + (size_t)(m0 - row_lo) * Fn;

  const bf16* agp = hb  + (size_t)(wid * 32 + lrow) * Fn + gseg * 8;
  const bf16* bgp = wde + (size_t)(n0 + wid * 32 + lrow) * Fn + gseg * 8;
  bf16* alp = As + wid * 32 * 32 + lane * 8;
  bf16* blp = Bs + wid * 32 * 32 + lane * 8;

  const int tt = (q ^ ((fr >> 1) & 3)) * 8;

  for (int kt = 0; kt < Fn / 32; ++kt) {   // 86 iters exact
    __syncthreads();
    gload16(agp, alp);
    gload16(agp + (size_t)16 * Fn, alp + 16 * 32);
    gload16(bgp, blp);
    gload16(bgp + (size_t)16 * Fn, blp + 16 * 32);
    agp += 32; bgp += 32;
    __syncthreads();

    bf16x8 a[4], bb[4];
#pragma unroll
    for (int mi = 0; mi < 4; ++mi)
      a[mi] = *(const bf16x8*)(As + (wm + mi * 16 + fr) * 32 + tt);
#pragma unroll
    for (int ni = 0; ni < 4; ++ni)
      bb[ni] = *(const bf16x8*)(Bs + (wn + ni * 16 + fr) * 32 + tt);
#pragma unroll
    for (int mi = 0; mi < 4; ++mi)
#pragma unroll
      for (int ni = 0; ni < 4; ++ni)
        acc[mi][ni] = __builtin_amdgcn_mfma_f32_16x16x32_bf16(a[mi], bb[ni], acc[mi][ni], 0, 0, 0);
  }

  const int rq = (lane >> 4) * 4, cl = lane & 15;
#pragma unroll
  for (int mi = 0; mi < 4; ++mi) {
#pragma unroll
    for (int r = 0; r < 4; ++r) {
      int grow = m0 + wm + mi * 16 + rq + r;
      bf16* orow = h2 + (size_t)grow * Cn + n0;
#pragma unroll
      for (int ni = 0; ni < 4; ++ni)
        orow[wn + ni * 16 + cl] = (bf16)acc[mi][ni][r];
    }
  }
}

// ---------------- combine: out[t] = h2[r0(t)] + h2[r1(t)] ---------------------
__global__ __launch_bounds__(256) void combine_kernel(
    const bf16* __restrict__ h2, const int* __restrict__ inv_rows,
    float* __restrict__ out)
{
  int t = blockIdx.x;
  int r0 = inv_rows[2 * t], r1 = inv_rows[2 * t + 1];
  int c = threadIdx.x * 4;
  bf16x4 a = *(const bf16x4*)(h2 + (size_t)r0 * Cn + c);
  bf16x4 b = *(const bf16x4*)(h2 + (size_t)r1 * Cn + c);
  float4 v;
  v.x = (float)a[0] + (float)b[0];
  v.y = (float)a[1] + (float)b[1];
  v.z = (float)a[2] + (float)b[2];
  v.w = (float)a[3] + (float)b[3];
  *(float4*)(out + (size_t)t * Cn + c) = v;
}

// ---------------- host launch ------------------------------------------------
extern "C" void kernel_launch(void* const* d_in, const int* in_sizes, int n_in,
                              void* d_out, int out_size, void* d_ws, size_t ws_size,
                              hipStream_t stream)
{
  const float* x     = (const float*)d_in[0];
  const float* wgate = (const float*)d_in[1];
  const float* wg    = (const float*)d_in[2];
  const float* wu    = (const float*)d_in[3];
  const float* wd    = (const float*)d_in[4];

  char* ws = (char*)d_ws;
  int* counts = (int*)ws;
  int* fill   = counts + 8;
  int* off    = fill + 8;
  size_t o = 256;
  int*   topk_i   = (int*)(ws + o);   o += (size_t)Tn * 2 * 4;
  float* topk_w   = (float*)(ws + o); o += (size_t)Tn * 2 * 4;
  int*   tok_list = (int*)(ws + o);   o += (size_t)MAXROWS * 4;
  float* wgt_list = (float*)(ws + o); o += (size_t)MAXROWS * 4;
  int*   inv_rows = (int*)(ws + o);   o += (size_t)Tn * 2 * 4;
  o = (o + 255) & ~(size_t)255;
  const size_t WSZ = (size_t)En * Fn * Cn;
  bf16* wgT = (bf16*)(ws + o); o += WSZ * 2;
  bf16* wuT = (bf16*)(ws + o); o += WSZ * 2;
  bf16* wdT = (bf16*)(ws + o); o += WSZ * 2;
  bf16* xg  = (bf16*)(ws + o); o += (size_t)MAXROWS * Cn * 2;
  bf16* h2  = (bf16*)(ws + o); o += (size_t)MAXROWS * Cn * 2;
  bf16* h   = (bf16*)(ws + o);

  size_t havail = ws_size > o ? ws_size - o : 0;
  long crows = (long)(havail / ((size_t)Fn * 2));
  crows &= ~(long)127;
  if (crows > MAXROWS) crows = MAXROWS;
  if (crows < 128) crows = 128;
  const int chunk_rows = (int)crows;
  const int nch = (MAXROWS + chunk_rows - 1) / chunk_rows;

  hipMemsetAsync(counts, 0, 256, stream);
  hipMemsetAsync(tok_list, 0xFF, (size_t)MAXROWS * 4, stream);

  transpose_cvt<<<dim3(Cn / 64, Fn / 64, En), 256, 0, stream>>>(wg, wgT, Cn, Fn);
  transpose_cvt<<<dim3(Cn / 64, Fn / 64, En), 256, 0, stream>>>(wu, wuT, Cn, Fn);
  transpose_cvt<<<dim3(Fn / 64, Cn / 64, En), 256, 0, stream>>>(wd, wdT, Fn, Cn);

  gate_kernel<<<Tn / 4, 256, 0, stream>>>(x, wgate, topk_i, topk_w, counts);
  offsets_kernel<<<1, 64, 0, stream>>>(counts, fill, off);
  scatter_kernel<<<Tn / 256, 256, 0, stream>>>(topk_i, topk_w, fill, tok_list, wgt_list, inv_rows);
  gather_x<<<MAXROWS, 256, 0, stream>>>(x, tok_list, xg);

  const int mt = chunk_rows / BM;
  const int nstripe = ((NT1 + 7) / 8) * 8;           // 48
  for (int c = 0; c < nch; ++c) {
    int row_lo = c * chunk_rows;
    gemm1_kernel<<<mt * nstripe, 256, 0, stream>>>(
        xg, wgT, wuT, off, counts, wgt_list, h, row_lo, mt);
    gemm2_kernel<<<mt * 8, 256, 0, stream>>>(
        h, wdT, off, h2, row_lo);
  }
  combine_kernel<<<Tn, 256, 0, stream>>>(h2, inv_rows, (float*)d_out);
}